// Round 7
// baseline (13031.812 us; speedup 1.0000x reference)
//
#include <hip/hip_runtime.h>
#include <cstdint>
#include <cstddef>

// Problem constants (fixed by setup_inputs)
#define HDIM 768
#define VOCAB 32000
#define NGATES 5
#define NJ 30
#define NB 16
#define NS 512
#define NBJ (NB*NJ)      // 480
#define G3 2304          // 3*H
#define PR 608           // padded state rows (max A-row read = 384+127 = 511)
#define NBV 250          // vocab n-blocks

typedef _Float16 f16;
typedef _Float16 f16x4 __attribute__((ext_vector_type(4)));
typedef _Float16 f16x8 __attribute__((ext_vector_type(8)));
typedef float f32x4 __attribute__((ext_vector_type(4)));

#define GLOBAL_AS __attribute__((address_space(1)))
#define LDS_AS    __attribute__((address_space(3)))

// One LDS arena shared by all phases (block-local, no cross-phase carryover).
union SharedU {
    struct { f16 a[8][128][8]; f16 b[8][128][8]; float sbuf[2][128]; } g;  // 33.8 KB (max)
    struct { float h[NJ][64]; float e[64][65]; } at;                       // 24.3 KB
    struct { float a[NJ][64]; } cx;                                        // 7.5 KB
    struct { float red[256]; float rv[256]; int ri[256]; } rd;             // 3 KB
};

// ---- hand-rolled grid barrier (monotone counter; all blocks co-resident) ----
__device__ __forceinline__ void gbar(unsigned* bar, unsigned nblk, unsigned& ph) {
    __syncthreads();                 // all waves' mem ops drained (vmcnt/lgkmcnt 0)
    ph += nblk;
    if (threadIdx.x == 0) {
        __threadfence();             // release: write back this XCD's L2
        __hip_atomic_fetch_add(bar, 1u, __ATOMIC_RELEASE, __HIP_MEMORY_SCOPE_AGENT);
        while (__hip_atomic_load(bar, __ATOMIC_ACQUIRE, __HIP_MEMORY_SCOPE_AGENT) < ph)
            __builtin_amdgcn_s_sleep(2);
        __threadfence();             // acquire: invalidate stale L1/L2 lines
    }
    __syncthreads();
}

// ---- split-f16 MFMA GEMM tile: C[bx*128..][by*128..] = A * B^T ----
// BM=BN=128, BK=64, 4 waves (2x2), wave tile 64x64; global_load_lds width-16
// staging into frag-major LDS [c][row][8]; A rows must be readable to m0+127.
__device__ __forceinline__ void gemm_tile(
        const f16* __restrict__ Ah, const f16* __restrict__ Al,
        const f16* __restrict__ Bh, const f16* __restrict__ Bl,
        float* __restrict__ Cf, f16* __restrict__ Ch, float* __restrict__ psum,
        int M, long ldc, int kdim, int nspan, int bx, int by, SharedU* sh) {
    const int tid = threadIdx.x;
    const int m0 = bx*128, n0 = by*128;
    const int w = tid >> 6, lane = tid & 63;
    const int wm = (w >> 1)*64, wn = (w & 1)*64;
    const int lr = lane & 15, lg = lane >> 4;

    f32x4 acc[4][4] = {};

    for (int sp = 0; sp < nspan; ++sp) {
        const f16* Ap = (sp < 2) ? Ah : Al;
        const f16* Bp = (sp == 1) ? Bl : Bh;
        for (int kc = 0; kc < kdim; kc += 64) {
            #pragma unroll
            for (int i = 0; i < 4; ++i) {
                const int idx = w*4 + i;                  // 0..15
                const int c = idx >> 1;                    // k-octet
                const int rl = (idx & 1)*64 + lane;        // row 0..127
                const f16* ga = Ap + (long)(m0 + rl)*kdim + kc + c*8;
                const f16* gb = Bp + (long)(n0 + rl)*kdim + kc + c*8;
                __builtin_amdgcn_global_load_lds(
                    (const GLOBAL_AS unsigned int*)ga,
                    (LDS_AS unsigned int*)((char*)&sh->g.a[0][0][0] + idx*1024), 16, 0, 0);
                __builtin_amdgcn_global_load_lds(
                    (const GLOBAL_AS unsigned int*)gb,
                    (LDS_AS unsigned int*)((char*)&sh->g.b[0][0][0] + idx*1024), 16, 0, 0);
            }
            __syncthreads();
            #pragma unroll
            for (int kk = 0; kk < 2; ++kk) {
                const int c = kk*4 + lg;
                f16x8 af[4], bf[4];
                #pragma unroll
                for (int mi = 0; mi < 4; ++mi) af[mi] = *(const f16x8*)&sh->g.a[c][wm + mi*16 + lr][0];
                #pragma unroll
                for (int nf = 0; nf < 4; ++nf) bf[nf] = *(const f16x8*)&sh->g.b[c][wn + nf*16 + lr][0];
                #pragma unroll
                for (int mi = 0; mi < 4; ++mi)
                    #pragma unroll
                    for (int nf = 0; nf < 4; ++nf)
                        acc[mi][nf] = __builtin_amdgcn_mfma_f32_16x16x32_f16(af[mi], bf[nf], acc[mi][nf], 0, 0, 0);
            }
            __syncthreads();
        }
    }

    // C write: layout col=lane&15, row=(lane>>4)*4+reg
    if (Ch != nullptr) {
        #pragma unroll
        for (int mi = 0; mi < 4; ++mi)
            #pragma unroll
            for (int nf = 0; nf < 4; ++nf) {
                int col = n0 + wn + nf*16 + lr;
                int rowb = m0 + wm + mi*16 + lg*4;
                #pragma unroll
                for (int r = 0; r < 4; ++r) {
                    int row = rowb + r;
                    if (row < M) Ch[(long)row*ldc + col] = (f16)acc[mi][nf][r];
                }
            }
    } else {
        #pragma unroll
        for (int mi = 0; mi < 4; ++mi)
            #pragma unroll
            for (int nf = 0; nf < 4; ++nf) {
                int col = n0 + wn + nf*16 + lr;
                int rowb = m0 + wm + mi*16 + lg*4;
                #pragma unroll
                for (int r = 0; r < 4; ++r) {
                    int row = rowb + r;
                    if (row < M) Cf[(long)row*ldc + col] = acc[mi][nf][r];
                }
            }
    }

    // fused row-sumexp partials over f16-rounded logits (no-max vocab softmax)
    if (psum != nullptr) {
        #pragma unroll
        for (int mi = 0; mi < 4; ++mi) {
            #pragma unroll
            for (int r = 0; r < 4; ++r) {
                float s = 0.f;
                #pragma unroll
                for (int nf = 0; nf < 4; ++nf) s += expf((float)(f16)acc[mi][nf][r]);
                s += __shfl_xor(s, 1); s += __shfl_xor(s, 2);
                s += __shfl_xor(s, 4); s += __shfl_xor(s, 8);
                if (lr == 0) sh->g.sbuf[w & 1][wm + mi*16 + lg*4 + r] = s;
            }
        }
        __syncthreads();
        if (tid < 128) psum[(long)by*512 + m0 + tid] = sh->g.sbuf[0][tid] + sh->g.sbuf[1][tid];
        __syncthreads();
    }
}

// ---- the whole decode in one kernel, phases separated by gbar ----
__launch_bounds__(256, 2)
__global__ void k_mega(const int* __restrict__ ids, const float* __restrict__ enc,
                       const float* __restrict__ hidden, const int* __restrict__ masks,
                       const int* __restrict__ slot, const float* __restrict__ E,
                       const float* __restrict__ Wih, const float* __restrict__ Whh,
                       const float* __restrict__ bih, const float* __restrict__ bhh,
                       const float* __restrict__ Wgen, const float* __restrict__ bgen,
                       const float* __restrict__ Wgate, const float* __restrict__ bgate,
                       float* __restrict__ out, float* __restrict__ gates_out, int ml,
                       f16* __restrict__ E16, f16* __restrict__ WH2, f16* __restrict__ WL2,
                       f16* __restrict__ SH, f16* __restrict__ SL,
                       float* __restrict__ gigh, float* __restrict__ hbuf,
                       float* __restrict__ ae, float* __restrict__ ctx,
                       f16* __restrict__ l16, float* __restrict__ pgen,
                       float* __restrict__ ps, unsigned* __restrict__ bar, int nblk) {
    __shared__ SharedU sh;
    __shared__ int s_bidx;
    unsigned ph = 0;

    const int blk = blockIdx.x, tid = threadIdx.x;
    f16* wH = SH;                       f16* wL = SL;
    f16* hH = SH + (size_t)PR*HDIM;     f16* hL = SL + (size_t)PR*HDIM;
    float* gi = gigh;                   float* gh = gigh + (size_t)NBJ*G3;
    const long ldrow = (long)ml*VOCAB;

    // ---------- phase 0: casts + init ----------
    {
        const long nE = (long)VOCAB*HDIM;
        for (long i = (long)(blk*256 + tid)*4; i < nE; i += (long)nblk*256*4) {
            float4 v = *(const float4*)&E[i];
            f16x4 o = { (f16)v.x, (f16)v.y, (f16)v.z, (f16)v.w };
            *(f16x4*)&E16[i] = o;
        }
        const long nW = (long)G3*HDIM;
        for (long i = (long)(blk*256 + tid)*4; i < nW; i += (long)nblk*256*4) {
            float4 a = *(const float4*)&Wih[i];
            f16x4 h = { (f16)a.x, (f16)a.y, (f16)a.z, (f16)a.w };
            f16x4 l = { (f16)(a.x-(float)h[0]), (f16)(a.y-(float)h[1]),
                        (f16)(a.z-(float)h[2]), (f16)(a.w-(float)h[3]) };
            *(f16x4*)&WH2[i] = h; *(f16x4*)&WL2[i] = l;
            float4 b = *(const float4*)&Whh[i];
            f16x4 h2 = { (f16)b.x, (f16)b.y, (f16)b.z, (f16)b.w };
            f16x4 l2 = { (f16)(b.x-(float)h2[0]), (f16)(b.y-(float)h2[1]),
                         (f16)(b.z-(float)h2[2]), (f16)(b.w-(float)h2[3]) };
            *(f16x4*)&WH2[nW + i] = h2; *(f16x4*)&WL2[nW + i] = l2;
        }
        for (int i = blk*256 + tid; i < NBJ*HDIM; i += nblk*256) {
            int hh = i % HDIM, row = i / HDIM;
            int b = row / NJ, j = row % NJ;
            float s = 0.f;
            #pragma unroll
            for (int l = 0; l < 4; ++l) s += E[(long)slot[j*4+l]*HDIM + hh];
            f16 sh16 = (f16)s;
            wH[i] = sh16; wL[i] = (f16)(s - (float)sh16);
            float hv = hidden[b*HDIM + hh];
            hbuf[i] = hv;
            f16 hh16 = (f16)hv;
            hH[i] = hh16; hL[i] = (f16)(hv - (float)hh16);
        }
    }
    gbar(bar, nblk, ph);

    for (int t = 0; t < ml; ++t) {
        // ---------- P1: GRU gemms (144 tiles): gi = w@Wih^T, gh = h@Whh^T ----------
        for (int bi = blk; bi < 144; bi += nblk) {
            int z = bi / 72, r = bi % 72, bx = r & 3, by = r >> 2;
            gemm_tile(z ? hH : wH, z ? hL : wL,
                      WH2 + (size_t)z*G3*HDIM, WL2 + (size_t)z*G3*HDIM,
                      z ? gh : gi, nullptr, nullptr,
                      NBJ, (long)G3, HDIM, 3, bx, by, &sh);
        }
        gbar(bar, nblk, ph);

        // ---------- P2: GRU elementwise ----------
        for (int i = blk*256 + tid; i < NBJ*HDIM; i += nblk*256) {
            int c = i % HDIM; long row = i / HDIM;
            long base = row*G3;
            float r = gi[base + c]         + bih[c]        + gh[base + c]         + bhh[c];
            float z = gi[base + 768 + c]   + bih[768 + c]  + gh[base + 768 + c]   + bhh[768 + c];
            float hn  = gh[base + 1536 + c] + bhh[1536 + c];
            float in_ = gi[base + 1536 + c] + bih[1536 + c];
            r = 1.f/(1.f + expf(-r));
            z = 1.f/(1.f + expf(-z));
            float n = tanhf(in_ + r*hn);
            float hv = (1.f - z)*n + z*hbuf[i];
            hbuf[i] = hv;
            f16 hh16 = (f16)hv;
            hH[i] = hh16; hL[i] = (f16)(hv - (float)hh16);
        }
        gbar(bar, nblk, ph);

        // ---------- P3: attention scores ae[row][s] (128 tiles, fp32) ----------
        for (int bi = blk; bi < 128; bi += nblk) {
            __syncthreads();
            const int b = bi >> 3, s0 = (bi & 7)*64;
            const int s = tid & 63, jg = tid >> 6;
            float acc[8] = {};
            for (int kc = 0; kc < HDIM; kc += 64) {
                for (int idx = tid; idx < NJ*64; idx += 256) {
                    int j = idx >> 6, k = idx & 63;
                    sh.at.h[j][k] = hbuf[((long)(b*NJ + j))*HDIM + kc + k];
                }
                #pragma unroll
                for (int i = 0; i < 4; ++i) {
                    int id = tid + i*256;
                    int ss = id >> 4, kq = (id & 15)*4;
                    float4 v = *(const float4*)&enc[((long)b*NS + s0 + ss)*HDIM + kc + kq];
                    sh.at.e[ss][kq+0] = v.x; sh.at.e[ss][kq+1] = v.y;
                    sh.at.e[ss][kq+2] = v.z; sh.at.e[ss][kq+3] = v.w;
                }
                __syncthreads();
                for (int k = 0; k < 64; ++k) {
                    float e = sh.at.e[s][k];
                    #pragma unroll
                    for (int i = 0; i < 8; ++i) {
                        int j = jg + i*4;
                        if (j < NJ) acc[i] += sh.at.h[j][k]*e;
                    }
                }
                __syncthreads();
            }
            #pragma unroll
            for (int i = 0; i < 8; ++i) {
                int j = jg + i*4;
                if (j < NJ) ae[((long)(b*NJ + j))*NS + s0 + s] = acc[i];
            }
        }
        gbar(bar, nblk, ph);

        // ---------- P4: masked softmax over S (in place) ----------
        for (int row = blk; row < NBJ; row += nblk) {
            __syncthreads();
            const int b = row / NJ;
            float x0 = ae[(long)row*NS + tid];
            float x1 = ae[(long)row*NS + tid + 256];
            if (masks[b*NS + tid]       != 1) x0 = -1e9f;
            if (masks[b*NS + tid + 256] != 1) x1 = -1e9f;
            sh.rd.red[tid] = fmaxf(x0, x1); __syncthreads();
            for (int o = 128; o > 0; o >>= 1) { if (tid < o) sh.rd.red[tid] = fmaxf(sh.rd.red[tid], sh.rd.red[tid+o]); __syncthreads(); }
            float m = sh.rd.red[0]; __syncthreads();
            float e0 = expf(x0 - m), e1 = expf(x1 - m);
            sh.rd.red[tid] = e0 + e1; __syncthreads();
            for (int o = 128; o > 0; o >>= 1) { if (tid < o) sh.rd.red[tid] += sh.rd.red[tid+o]; __syncthreads(); }
            float inv = 1.f/sh.rd.red[0];
            ae[(long)row*NS + tid]       = e0*inv;
            ae[(long)row*NS + tid + 256] = e1*inv;
        }
        gbar(bar, nblk, ph);

        // ---------- P5: context (96 tiles; enc read exactly once) ----------
        for (int bi = blk; bi < 96; bi += nblk) {
            __syncthreads();
            const int b = bi / 6, ht = bi % 6;
            const int hh = ht*128 + (tid & 127);
            const int jg = tid >> 7;
            float acc[15] = {};
            for (int sc = 0; sc < NS; sc += 64) {
                for (int idx = tid; idx < NJ*64; idx += 256) {
                    int j = idx >> 6, s = idx & 63;
                    sh.cx.a[j][s] = ae[((long)(b*NJ + j))*NS + sc + s];
                }
                __syncthreads();
                for (int s = 0; s < 64; ++s) {
                    float e = enc[((long)b*NS + sc + s)*HDIM + hh];
                    #pragma unroll
                    for (int i = 0; i < 15; ++i) acc[i] += sh.cx.a[jg + i*2][s]*e;
                }
                __syncthreads();
            }
            #pragma unroll
            for (int i = 0; i < 15; ++i) ctx[((long)(b*NJ + jg + i*2))*HDIM + hh] = acc[i];
        }
        gbar(bar, nblk, ph);

        // ---------- P6: p_gen (+ gates at t==0) ----------
        for (int row = blk; row < NBJ; row += nblk) {
            __syncthreads();
            float acc = 0.f;
            for (int x = tid; x < HDIM; x += 256) {
                float wv = (float)wH[(long)row*HDIM + x] + (float)wL[(long)row*HDIM + x];
                acc += wv*Wgen[x] + hbuf[(long)row*HDIM + x]*Wgen[768 + x]
                     + ctx[(long)row*HDIM + x]*Wgen[1536 + x];
            }
            sh.rd.red[tid] = acc; __syncthreads();
            for (int o = 128; o > 0; o >>= 1) { if (tid < o) sh.rd.red[tid] += sh.rd.red[tid+o]; __syncthreads(); }
            if (tid == 0) pgen[row] = 1.f/(1.f + expf(-(sh.rd.red[0] + bgen[0])));
            if (t == 0) {
                for (int g = 0; g < NGATES; ++g) {
                    __syncthreads();
                    float a = 0.f;
                    for (int x = tid; x < HDIM; x += 256) a += ctx[(long)row*HDIM + x]*Wgate[x*NGATES + g];
                    sh.rd.red[tid] = a; __syncthreads();
                    for (int o = 128; o > 0; o >>= 1) { if (tid < o) sh.rd.red[tid] += sh.rd.red[tid+o]; __syncthreads(); }
                    if (tid == 0) gates_out[row*NGATES + g] = sh.rd.red[0] + bgate[g];
                }
            }
        }
        gbar(bar, nblk, ph);

        // ---------- P7: vocab logits (1000 tiles, f16 out + fused sumexp) ----------
        for (int vt = blk; vt < 4*NBV; vt += nblk) {
            gemm_tile(hH, nullptr, E16, nullptr, nullptr, l16, ps,
                      NBJ, (long)VOCAB, HDIM, 1, vt & 3, vt >> 2, &sh);
        }
        gbar(bar, nblk, ph);

        // ---------- P8: finalize — scale + argmax + pointer scatter + next-w ----------
        for (int row = blk; row < NBJ; row += nblk) {
            __syncthreads();
            const int b = row / NJ;
            float* base = out + (long)row*ldrow + (long)t*VOCAB;
            const f16* lb = l16 + (long)row*VOCAB;
            float s = 0.f;
            for (int nb = tid; nb < NBV; nb += 256) s += ps[(long)nb*512 + row];
            sh.rd.red[tid] = s; __syncthreads();
            for (int o = 128; o > 0; o >>= 1) { if (tid < o) sh.rd.red[tid] += sh.rd.red[tid+o]; __syncthreads(); }
            const float pg = pgen[row];
            const float scale = pg / sh.rd.red[0];

            float bv = -1.f; int bi = 0;
            for (int v = tid; v < VOCAB; v += 256) {
                float val = scale*expf((float)lb[v]);
                base[v] = val;
                if (val > bv) { bv = val; bi = v; }   // strict ">" keeps smallest index per thread
            }
            sh.rd.rv[tid] = bv; sh.rd.ri[tid] = bi; __syncthreads();
            for (int o = 128; o > 0; o >>= 1) {
                if (tid < o) {
                    float v2 = sh.rd.rv[tid+o]; int i2 = sh.rd.ri[tid+o];
                    if (v2 > sh.rd.rv[tid] || (v2 == sh.rd.rv[tid] && i2 < sh.rd.ri[tid])) { sh.rd.rv[tid] = v2; sh.rd.ri[tid] = i2; }
                }
                __syncthreads();
            }
            float v0 = sh.rd.rv[0]; int i0 = sh.rd.ri[0];
            __syncthreads();   // all base[] stores drained before atomics

            const float cp = 1.f - pg;
            float sv = -1.f; int si = 0x7FFFFFFF;
            for (int ss = tid; ss < NS; ss += 256) {
                int id = ids[(long)b*NS + ss];
                float add = cp * ae[(long)row*NS + ss];
                float old = atomicAdd(base + id, add);
                float cand = old + add;   // temporally-last add on an address yields its true final value
                if (cand > sv || (cand == sv && id < si)) { sv = cand; si = id; }
            }
            sh.rd.rv[tid] = sv; sh.rd.ri[tid] = si; __syncthreads();
            for (int o = 128; o > 0; o >>= 1) {
                if (tid < o) {
                    float v2 = sh.rd.rv[tid+o]; int i2 = sh.rd.ri[tid+o];
                    if (v2 > sh.rd.rv[tid] || (v2 == sh.rd.rv[tid] && i2 < sh.rd.ri[tid])) { sh.rd.rv[tid] = v2; sh.rd.ri[tid] = i2; }
                }
                __syncthreads();
            }
            if (tid == 0) {
                float vv = v0; int ii = i0;
                if (sh.rd.rv[0] > vv || (sh.rd.rv[0] == vv && sh.rd.ri[0] < ii)) { vv = sh.rd.rv[0]; ii = sh.rd.ri[0]; }
                s_bidx = ii;
            }
            __syncthreads();
            const int idx = s_bidx;
            for (int x = tid; x < HDIM; x += 256) {
                float ev = E[(long)idx*HDIM + x];
                f16 eh = (f16)ev;
                wH[(long)row*HDIM + x] = eh;
                wL[(long)row*HDIM + x] = (f16)(ev - (float)eh);
            }
        }
        gbar(bar, nblk, ph);
    }
}

// ---------------- host ----------------
extern "C" void kernel_launch(void* const* d_in, const int* in_sizes, int n_in,
                              void* d_out, int out_size, void* d_ws, size_t ws_size,
                              hipStream_t stream) {
    const int*   input_ids = (const int*)  d_in[0];
    const float* enc       = (const float*)d_in[1];
    const float* hidden    = (const float*)d_in[2];
    const int*   masks     = (const int*)  d_in[3];
    const int*   slot      = (const int*)  d_in[4];
    const float* E     = (const float*)d_in[6];
    const float* Wih   = (const float*)d_in[7];
    const float* Whh   = (const float*)d_in[8];
    const float* bih   = (const float*)d_in[9];
    const float* bhh   = (const float*)d_in[10];
    const float* Wgen  = (const float*)d_in[11];
    const float* bgen  = (const float*)d_in[12];
    const float* Wgate = (const float*)d_in[13];
    const float* bgate = (const float*)d_in[14];

    int ml = (out_size / NBJ - NGATES) / VOCAB;   // = 8
    float* out = (float*)d_out;
    float* gates_out = out + (long)NBJ*ml*VOCAB;

    // workspace carve (256B aligned)
    char* ws = (char*)d_ws;
    auto carve = [&](size_t bytes) { char* p = ws; ws += (bytes + 255) & ~(size_t)255; return p; };
    unsigned* bar = (unsigned*)carve(256);
    f16*   E16   = (f16*)carve((size_t)VOCAB*HDIM*2);
    f16*   WH2   = (f16*)carve((size_t)2*G3*HDIM*2);   // WihH | WhhH
    f16*   WL2   = (f16*)carve((size_t)2*G3*HDIM*2);
    f16*   SH    = (f16*)carve((size_t)2*PR*HDIM*2);   // wH | hH (padded rows)
    f16*   SL    = (f16*)carve((size_t)2*PR*HDIM*2);
    float* gigh  = (float*)carve((size_t)2*NBJ*G3*4);  // gi | gh
    float* hbuf  = (float*)carve((size_t)NBJ*HDIM*4);
    float* ae    = (float*)carve((size_t)NBJ*NS*4);
    float* ctx   = (float*)carve((size_t)NBJ*HDIM*4);
    f16*   l16   = (f16*)carve((size_t)NBJ*VOCAB*2);
    float* pgen  = (float*)carve((size_t)NBJ*4);
    float* ps    = (float*)carve((size_t)NBV*512*4);

    // co-residency-safe grid size from the runtime's own occupancy model
    int dev = 0; (void)hipGetDevice(&dev);
    int ncu = 0; (void)hipDeviceGetAttribute(&ncu, hipDeviceAttributeMultiprocessorCount, dev);
    int occ = 0; (void)hipOccupancyMaxActiveBlocksPerMultiprocessor(&occ, (const void*)k_mega, 256, 0);
    if (ncu <= 0) ncu = 256;
    if (occ <= 0) occ = 1;
    long cap = (long)occ * (long)ncu;
    int nblk = (int)(cap < 512 ? cap : 512);

    (void)hipMemsetAsync(bar, 0, sizeof(unsigned), stream);
    k_mega<<<dim3(nblk), dim3(256), 0, stream>>>(
        input_ids, enc, hidden, masks, slot, E, Wih, Whh, bih, bhh,
        Wgen, bgen, Wgate, bgate, out, gates_out, ml,
        E16, WH2, WL2, SH, SL, gigh, hbuf, ae, ctx, l16, pgen, ps, bar, nblk);
}

// Round 10
// 6850.407 us; speedup vs baseline: 1.9023x; 1.9023x over previous
//
#include <hip/hip_runtime.h>
#include <cstdint>
#include <cstddef>

// Problem constants (fixed by setup_inputs)
#define HDIM 768
#define VOCAB 32000
#define NGATES 5
#define NJ 30
#define NB 16
#define NS 512
#define NBJ (NB*NJ)      // 480
#define G3 2304          // 3*H
#define PR 608           // padded state rows
#define NBV 250          // vocab n-blocks

typedef _Float16 f16;
typedef _Float16 f16x4 __attribute__((ext_vector_type(4)));
typedef _Float16 f16x8 __attribute__((ext_vector_type(8)));
typedef float f32x4 __attribute__((ext_vector_type(4)));

#define GLOBAL_AS __attribute__((address_space(1)))
#define LDS_AS    __attribute__((address_space(3)))

// ---- grid barrier: fences hoisted OUT of the poll loop ----
// release wb -> relaxed add -> relaxed polls (R9 proved they observe the
// counter) -> ONE acquire inv. R7 semantics at ~1/100th the fence count.
__device__ __forceinline__ void gbar(unsigned* bar, unsigned nblk, unsigned& ph) {
    __syncthreads();
    ph += nblk;
    if (threadIdx.x == 0) {
        __threadfence();   // release: write back this XCD's L2 (once)
        __hip_atomic_fetch_add(bar, 1u, __ATOMIC_RELAXED, __HIP_MEMORY_SCOPE_AGENT);
        while (__hip_atomic_load(bar, __ATOMIC_RELAXED, __HIP_MEMORY_SCOPE_AGENT) < ph)
            __builtin_amdgcn_s_sleep(32);
        __threadfence();   // acquire: invalidate stale lines (once)
    }
    __syncthreads();
}

// One LDS arena shared by all phases (block-local).
union SharedU {
    struct { f16 a[8][128][8]; f16 b[8][128][8]; float sbuf[2][128]; } g;  // 33.8 KB
    struct { float h[NJ][64]; float e[64][65]; } at;                       // 24.3 KB
    struct { float a[NJ][64]; } cx;                                        // 7.5 KB
    struct { float red[256]; float rv[256]; int ri[256]; } rd;             // 3 KB
};

// ---- split-f16 MFMA GEMM tile: C[bx*128..][by*128..] = A * B^T (R7-proven) ----
__device__ __forceinline__ void gemm_tile(
        const f16* __restrict__ Ah, const f16* __restrict__ Al,
        const f16* __restrict__ Bh, const f16* __restrict__ Bl,
        float* __restrict__ Cf, f16* __restrict__ Ch, float* __restrict__ psum,
        int M, long ldc, int kdim, int nspan, int bx, int by, SharedU* sh) {
    const int tid = threadIdx.x;
    const int m0 = bx*128, n0 = by*128;
    const int w = tid >> 6, lane = tid & 63;
    const int wm = (w >> 1)*64, wn = (w & 1)*64;
    const int lr = lane & 15, lg = lane >> 4;

    f32x4 acc[4][4] = {};

    for (int sp = 0; sp < nspan; ++sp) {
        const f16* Ap = (sp < 2) ? Ah : Al;
        const f16* Bp = (sp == 1) ? Bl : Bh;
        for (int kc = 0; kc < kdim; kc += 64) {
            #pragma unroll
            for (int i = 0; i < 4; ++i) {
                const int idx = w*4 + i;                  // 0..15
                const int c = idx >> 1;                    // k-octet
                const int rl = (idx & 1)*64 + lane;        // row 0..127
                const f16* ga = Ap + (long)(m0 + rl)*kdim + kc + c*8;
                const f16* gb = Bp + (long)(n0 + rl)*kdim + kc + c*8;
                __builtin_amdgcn_global_load_lds(
                    (const GLOBAL_AS unsigned int*)ga,
                    (LDS_AS unsigned int*)((char*)&sh->g.a[0][0][0] + idx*1024), 16, 0, 0);
                __builtin_amdgcn_global_load_lds(
                    (const GLOBAL_AS unsigned int*)gb,
                    (LDS_AS unsigned int*)((char*)&sh->g.b[0][0][0] + idx*1024), 16, 0, 0);
            }
            __syncthreads();
            #pragma unroll
            for (int kk = 0; kk < 2; ++kk) {
                const int c = kk*4 + lg;
                f16x8 af[4], bf[4];
                #pragma unroll
                for (int mi = 0; mi < 4; ++mi) af[mi] = *(const f16x8*)&sh->g.a[c][wm + mi*16 + lr][0];
                #pragma unroll
                for (int nf = 0; nf < 4; ++nf) bf[nf] = *(const f16x8*)&sh->g.b[c][wn + nf*16 + lr][0];
                #pragma unroll
                for (int mi = 0; mi < 4; ++mi)
                    #pragma unroll
                    for (int nf = 0; nf < 4; ++nf)
                        acc[mi][nf] = __builtin_amdgcn_mfma_f32_16x16x32_f16(af[mi], bf[nf], acc[mi][nf], 0, 0, 0);
            }
            __syncthreads();
        }
    }

    if (Ch != nullptr) {
        #pragma unroll
        for (int mi = 0; mi < 4; ++mi)
            #pragma unroll
            for (int nf = 0; nf < 4; ++nf) {
                int col = n0 + wn + nf*16 + lr;
                int rowb = m0 + wm + mi*16 + lg*4;
                #pragma unroll
                for (int r = 0; r < 4; ++r) {
                    int row = rowb + r;
                    if (row < M) Ch[(long)row*ldc + col] = (f16)acc[mi][nf][r];
                }
            }
    } else {
        #pragma unroll
        for (int mi = 0; mi < 4; ++mi)
            #pragma unroll
            for (int nf = 0; nf < 4; ++nf) {
                int col = n0 + wn + nf*16 + lr;
                int rowb = m0 + wm + mi*16 + lg*4;
                #pragma unroll
                for (int r = 0; r < 4; ++r) {
                    int row = rowb + r;
                    if (row < M) Cf[(long)row*ldc + col] = acc[mi][nf][r];
                }
            }
    }

    // fused row-sumexp partials over f16-rounded logits (no-max vocab softmax)
    if (psum != nullptr) {
        #pragma unroll
        for (int mi = 0; mi < 4; ++mi) {
            #pragma unroll
            for (int r = 0; r < 4; ++r) {
                float s = 0.f;
                #pragma unroll
                for (int nf = 0; nf < 4; ++nf) s += expf((float)(f16)acc[mi][nf][r]);
                s += __shfl_xor(s, 1); s += __shfl_xor(s, 2);
                s += __shfl_xor(s, 4); s += __shfl_xor(s, 8);
                if (lr == 0) sh->g.sbuf[w & 1][wm + mi*16 + lg*4 + r] = s;
            }
        }
        __syncthreads();
        if (tid < 128) psum[(long)by*512 + m0 + tid] = sh->g.sbuf[0][tid] + sh->g.sbuf[1][tid];
        __syncthreads();
    }
}

// ---- the whole decode in one kernel; 6 barriers per step ----
__launch_bounds__(256, 2)
__global__ void k_mega(const int* __restrict__ ids, const float* __restrict__ enc,
                       const float* __restrict__ hidden, const int* __restrict__ masks,
                       const int* __restrict__ slot, const float* __restrict__ E,
                       const float* __restrict__ Wih, const float* __restrict__ Whh,
                       const float* __restrict__ bih, const float* __restrict__ bhh,
                       const float* __restrict__ Wgen, const float* __restrict__ bgen,
                       const float* __restrict__ Wgate, const float* __restrict__ bgate,
                       float* __restrict__ out, float* __restrict__ gates_out, int ml,
                       f16* __restrict__ E16, f16* __restrict__ WH2, f16* __restrict__ WL2,
                       f16* __restrict__ SH, f16* __restrict__ SL,
                       float* __restrict__ gigh, float* __restrict__ hbuf,
                       float* __restrict__ ae, float* __restrict__ ctx,
                       f16* __restrict__ l16, float* __restrict__ ps,
                       unsigned* __restrict__ bar, int nblk) {
    __shared__ SharedU sh;
    __shared__ int s_bidx;
    unsigned ph = 0;

    const int blk = blockIdx.x, tid = threadIdx.x;
    f16* wH = SH;                       f16* wL = SL;
    f16* hH = SH + (size_t)PR*HDIM;     f16* hL = SL + (size_t)PR*HDIM;
    float* gi = gigh;                   float* gh = gigh + (size_t)NBJ*G3;
    const long ldrow = (long)ml*VOCAB;

    // ---------- phase 0: casts + init ----------
    {
        const long nE = (long)VOCAB*HDIM;
        for (long i = (long)(blk*256 + tid)*4; i < nE; i += (long)nblk*256*4) {
            float4 v = *(const float4*)&E[i];
            f16x4 o = { (f16)v.x, (f16)v.y, (f16)v.z, (f16)v.w };
            *(f16x4*)&E16[i] = o;
        }
        const long nW = (long)G3*HDIM;
        for (long i = (long)(blk*256 + tid)*4; i < nW; i += (long)nblk*256*4) {
            float4 a = *(const float4*)&Wih[i];
            f16x4 h = { (f16)a.x, (f16)a.y, (f16)a.z, (f16)a.w };
            f16x4 l = { (f16)(a.x-(float)h[0]), (f16)(a.y-(float)h[1]),
                        (f16)(a.z-(float)h[2]), (f16)(a.w-(float)h[3]) };
            *(f16x4*)&WH2[i] = h; *(f16x4*)&WL2[i] = l;
            float4 b = *(const float4*)&Whh[i];
            f16x4 h2 = { (f16)b.x, (f16)b.y, (f16)b.z, (f16)b.w };
            f16x4 l2 = { (f16)(b.x-(float)h2[0]), (f16)(b.y-(float)h2[1]),
                         (f16)(b.z-(float)h2[2]), (f16)(b.w-(float)h2[3]) };
            *(f16x4*)&WH2[nW + i] = h2; *(f16x4*)&WL2[nW + i] = l2;
        }
        for (int i = blk*256 + tid; i < NBJ*HDIM; i += nblk*256) {
            int hh = i % HDIM, row = i / HDIM;
            int b = row / NJ, j = row % NJ;
            float s = 0.f;
            #pragma unroll
            for (int l = 0; l < 4; ++l) s += E[(long)slot[j*4+l]*HDIM + hh];
            f16 sh16 = (f16)s;
            wH[i] = sh16; wL[i] = (f16)(s - (float)sh16);
            float hv = hidden[b*HDIM + hh];
            hbuf[i] = hv;
            f16 hh16 = (f16)hv;
            hH[i] = hh16; hL[i] = (f16)(hv - (float)hh16);
        }
    }
    gbar(bar, nblk, ph);

    for (int t = 0; t < ml; ++t) {
        // ---------- P1: GRU gemms (144 tiles) ----------
        for (int bi = blk; bi < 144; bi += nblk) {
            int z = bi / 72, r = bi % 72, bx = r & 3, by = r >> 2;
            gemm_tile(z ? hH : wH, z ? hL : wL,
                      WH2 + (size_t)z*G3*HDIM, WL2 + (size_t)z*G3*HDIM,
                      z ? gh : gi, nullptr, nullptr,
                      NBJ, (long)G3, HDIM, 3, bx, by, &sh);
        }
        gbar(bar, nblk, ph);

        // ---------- P2: GRU elementwise ----------
        for (int i = blk*256 + tid; i < NBJ*HDIM; i += nblk*256) {
            int c = i % HDIM; long row = i / HDIM;
            long base = row*G3;
            float r = gi[base + c]         + bih[c]        + gh[base + c]         + bhh[c];
            float z = gi[base + 768 + c]   + bih[768 + c]  + gh[base + 768 + c]   + bhh[768 + c];
            float hn  = gh[base + 1536 + c] + bhh[1536 + c];
            float in_ = gi[base + 1536 + c] + bih[1536 + c];
            r = 1.f/(1.f + expf(-r));
            z = 1.f/(1.f + expf(-z));
            float n = tanhf(in_ + r*hn);
            float hv = (1.f - z)*n + z*hbuf[i];
            hbuf[i] = hv;
            f16 hh16 = (f16)hv;
            hH[i] = hh16; hL[i] = (f16)(hv - (float)hh16);
        }
        gbar(bar, nblk, ph);

        // ---------- PA: attn scores (128 units) + vocab logits (1000 units) ----------
        for (int u = blk; u < 128 + 4*NBV; u += nblk) {
            __syncthreads();   // guard LDS arena reuse between loop iterations
            if (u < 128) {
                const int b = u >> 3, s0 = (u & 7)*64;
                const int s = tid & 63, jg = tid >> 6;
                float acc[8] = {};
                for (int kc = 0; kc < HDIM; kc += 64) {
                    for (int idx = tid; idx < NJ*64; idx += 256) {
                        int j = idx >> 6, k = idx & 63;
                        sh.at.h[j][k] = hbuf[((long)(b*NJ + j))*HDIM + kc + k];
                    }
                    #pragma unroll
                    for (int i = 0; i < 4; ++i) {
                        int id = tid + i*256;
                        int ss = id >> 4, kq = (id & 15)*4;
                        float4 v = *(const float4*)&enc[((long)b*NS + s0 + ss)*HDIM + kc + kq];
                        sh.at.e[ss][kq+0] = v.x; sh.at.e[ss][kq+1] = v.y;
                        sh.at.e[ss][kq+2] = v.z; sh.at.e[ss][kq+3] = v.w;
                    }
                    __syncthreads();
                    for (int k = 0; k < 64; ++k) {
                        float e = sh.at.e[s][k];
                        #pragma unroll
                        for (int i = 0; i < 8; ++i) {
                            int j = jg + i*4;
                            if (j < NJ) acc[i] += sh.at.h[j][k]*e;
                        }
                    }
                    __syncthreads();
                }
                #pragma unroll
                for (int i = 0; i < 8; ++i) {
                    int j = jg + i*4;
                    if (j < NJ) ae[((long)(b*NJ + j))*NS + s0 + s] = acc[i];
                }
            } else {
                const int vt = u - 128;
                gemm_tile(hH, nullptr, E16, nullptr, nullptr, l16, ps,
                          NBJ, (long)VOCAB, HDIM, 1, vt & 3, vt >> 2, &sh);
            }
        }
        gbar(bar, nblk, ph);

        // ---------- P4: masked softmax over S (in place) ----------
        for (int row = blk; row < NBJ; row += nblk) {
            __syncthreads();
            const int b = row / NJ;
            float x0 = ae[(long)row*NS + tid];
            float x1 = ae[(long)row*NS + tid + 256];
            if (masks[b*NS + tid]       != 1) x0 = -1e9f;
            if (masks[b*NS + tid + 256] != 1) x1 = -1e9f;
            sh.rd.red[tid] = fmaxf(x0, x1); __syncthreads();
            for (int o = 128; o > 0; o >>= 1) { if (tid < o) sh.rd.red[tid] = fmaxf(sh.rd.red[tid], sh.rd.red[tid+o]); __syncthreads(); }
            float m = sh.rd.red[0]; __syncthreads();
            float e0 = expf(x0 - m), e1 = expf(x1 - m);
            sh.rd.red[tid] = e0 + e1; __syncthreads();
            for (int o = 128; o > 0; o >>= 1) { if (tid < o) sh.rd.red[tid] += sh.rd.red[tid+o]; __syncthreads(); }
            float inv = 1.f/sh.rd.red[0];
            ae[(long)row*NS + tid]       = e0*inv;
            ae[(long)row*NS + tid + 256] = e1*inv;
        }
        gbar(bar, nblk, ph);

        // ---------- P5: context (96 tiles; enc read exactly once) ----------
        for (int bi = blk; bi < 96; bi += nblk) {
            __syncthreads();
            const int b = bi / 6, ht = bi % 6;
            const int hh = ht*128 + (tid & 127);
            const int jg = tid >> 7;
            float acc[15] = {};
            for (int sc = 0; sc < NS; sc += 64) {
                for (int idx = tid; idx < NJ*64; idx += 256) {
                    int j = idx >> 6, s = idx & 63;
                    sh.cx.a[j][s] = ae[((long)(b*NJ + j))*NS + sc + s];
                }
                __syncthreads();
                for (int s = 0; s < 64; ++s) {
                    float e = enc[((long)b*NS + sc + s)*HDIM + hh];
                    #pragma unroll
                    for (int i = 0; i < 15; ++i) acc[i] += sh.cx.a[jg + i*2][s]*e;
                }
                __syncthreads();
            }
            #pragma unroll
            for (int i = 0; i < 15; ++i) ctx[((long)(b*NJ + jg + i*2))*HDIM + hh] = acc[i];
        }
        gbar(bar, nblk, ph);

        // ---------- P8: finalize — pgen(+gates) + scale + argmax + scatter + next-w ----------
        for (int row = blk; row < NBJ; row += nblk) {
            __syncthreads();
            const int b = row / NJ;
            float* base = out + (long)row*ldrow + (long)t*VOCAB;
            const f16* lb = l16 + (long)row*VOCAB;

            // p_gen = sigmoid([w,h,ctx] . Wgen + b)
            float acc = 0.f;
            for (int x = tid; x < HDIM; x += 256) {
                float wv = (float)wH[(long)row*HDIM + x] + (float)wL[(long)row*HDIM + x];
                acc += wv*Wgen[x] + hbuf[(long)row*HDIM + x]*Wgen[768 + x]
                     + ctx[(long)row*HDIM + x]*Wgen[1536 + x];
            }
            sh.rd.red[tid] = acc; __syncthreads();
            for (int o = 128; o > 0; o >>= 1) { if (tid < o) sh.rd.red[tid] += sh.rd.red[tid+o]; __syncthreads(); }
            const float pg = 1.f/(1.f + expf(-(sh.rd.red[0] + bgen[0])));
            __syncthreads();

            if (t == 0) {
                for (int g = 0; g < NGATES; ++g) {
                    float a = 0.f;
                    for (int x = tid; x < HDIM; x += 256) a += ctx[(long)row*HDIM + x]*Wgate[x*NGATES + g];
                    sh.rd.red[tid] = a; __syncthreads();
                    for (int o = 128; o > 0; o >>= 1) { if (tid < o) sh.rd.red[tid] += sh.rd.red[tid+o]; __syncthreads(); }
                    if (tid == 0) gates_out[row*NGATES + g] = sh.rd.red[0] + bgate[g];
                    __syncthreads();
                }
            }

            // denominator from psum partials
            float s = 0.f;
            for (int nb = tid; nb < NBV; nb += 256) s += ps[(long)nb*512 + row];
            sh.rd.red[tid] = s; __syncthreads();
            for (int o = 128; o > 0; o >>= 1) { if (tid < o) sh.rd.red[tid] += sh.rd.red[tid+o]; __syncthreads(); }
            const float scale = pg / sh.rd.red[0];

            // p = pgen*exp(l)/sum, track argmax (first-index ties)
            float bv = -1.f; int bi = 0;
            for (int v = tid; v < VOCAB; v += 256) {
                float val = scale*expf((float)lb[v]);
                base[v] = val;
                if (val > bv) { bv = val; bi = v; }
            }
            sh.rd.rv[tid] = bv; sh.rd.ri[tid] = bi; __syncthreads();
            for (int o = 128; o > 0; o >>= 1) {
                if (tid < o) {
                    float v2 = sh.rd.rv[tid+o]; int i2 = sh.rd.ri[tid+o];
                    if (v2 > sh.rd.rv[tid] || (v2 == sh.rd.rv[tid] && i2 < sh.rd.ri[tid])) { sh.rd.rv[tid] = v2; sh.rd.ri[tid] = i2; }
                }
                __syncthreads();
            }
            float v0 = sh.rd.rv[0]; int i0 = sh.rd.ri[0];
            __syncthreads();   // base[] stores drained (implied waitcnt) before atomics

            // pointer scatter; temporally-last add on an address = true final value
            const float cp = 1.f - pg;
            float sv = -1.f; int si = 0x7FFFFFFF;
            for (int ss = tid; ss < NS; ss += 256) {
                int id = ids[(long)b*NS + ss];
                float add = cp * ae[(long)row*NS + ss];
                float old = atomicAdd(base + id, add);
                float cand = old + add;
                if (cand > sv || (cand == sv && id < si)) { sv = cand; si = id; }
            }
            sh.rd.rv[tid] = sv; sh.rd.ri[tid] = si; __syncthreads();
            for (int o = 128; o > 0; o >>= 1) {
                if (tid < o) {
                    float v2 = sh.rd.rv[tid+o]; int i2 = sh.rd.ri[tid+o];
                    if (v2 > sh.rd.rv[tid] || (v2 == sh.rd.rv[tid] && i2 < sh.rd.ri[tid])) { sh.rd.rv[tid] = v2; sh.rd.ri[tid] = i2; }
                }
                __syncthreads();
            }
            if (tid == 0) {
                float vv = v0; int ii = i0;
                if (sh.rd.rv[0] > vv || (sh.rd.rv[0] == vv && sh.rd.ri[0] < ii)) { vv = sh.rd.rv[0]; ii = sh.rd.ri[0]; }
                s_bidx = ii;
            }
            __syncthreads();
            const int idx = s_bidx;
            for (int x = tid; x < HDIM; x += 256) {
                float ev = E[(long)idx*HDIM + x];
                f16 eh = (f16)ev;
                wH[(long)row*HDIM + x] = eh;
                wL[(long)row*HDIM + x] = (f16)(ev - (float)eh);
            }
        }
        gbar(bar, nblk, ph);
    }
}

// ---------------- host ----------------
extern "C" void kernel_launch(void* const* d_in, const int* in_sizes, int n_in,
                              void* d_out, int out_size, void* d_ws, size_t ws_size,
                              hipStream_t stream) {
    const int*   input_ids = (const int*)  d_in[0];
    const float* enc       = (const float*)d_in[1];
    const float* hidden    = (const float*)d_in[2];
    const int*   masks     = (const int*)  d_in[3];
    const int*   slot      = (const int*)  d_in[4];
    const float* E     = (const float*)d_in[6];
    const float* Wih   = (const float*)d_in[7];
    const float* Whh   = (const float*)d_in[8];
    const float* bih   = (const float*)d_in[9];
    const float* bhh   = (const float*)d_in[10];
    const float* Wgen  = (const float*)d_in[11];
    const float* bgen  = (const float*)d_in[12];
    const float* Wgate = (const float*)d_in[13];
    const float* bgate = (const float*)d_in[14];

    int ml = (out_size / NBJ - NGATES) / VOCAB;   // = 8
    float* out = (float*)d_out;
    float* gates_out = out + (long)NBJ*ml*VOCAB;

    // workspace carve (256B aligned)
    char* ws = (char*)d_ws;
    auto carve = [&](size_t bytes) { char* p = ws; ws += (bytes + 255) & ~(size_t)255; return p; };
    unsigned* bar = (unsigned*)carve(256);
    f16*   E16   = (f16*)carve((size_t)VOCAB*HDIM*2);
    f16*   WH2   = (f16*)carve((size_t)2*G3*HDIM*2);   // WihH | WhhH
    f16*   WL2   = (f16*)carve((size_t)2*G3*HDIM*2);
    f16*   SH    = (f16*)carve((size_t)2*PR*HDIM*2);   // wH | hH (padded rows)
    f16*   SL    = (f16*)carve((size_t)2*PR*HDIM*2);
    float* gigh  = (float*)carve((size_t)2*NBJ*G3*4);  // gi | gh
    float* hbuf  = (float*)carve((size_t)NBJ*HDIM*4);
    float* ae    = (float*)carve((size_t)NBJ*NS*4);
    float* ctx   = (float*)carve((size_t)NBJ*HDIM*4);
    f16*   l16   = (f16*)carve((size_t)NBJ*VOCAB*2);
    float* ps    = (float*)carve((size_t)NBV*512*4);

    // co-residency-safe grid size (R7 ran to completion at 512 -> co-resident)
    int dev = 0; (void)hipGetDevice(&dev);
    int ncu = 0; (void)hipDeviceGetAttribute(&ncu, hipDeviceAttributeMultiprocessorCount, dev);
    int occ = 0; (void)hipOccupancyMaxActiveBlocksPerMultiprocessor(&occ, (const void*)k_mega, 256, 0);
    if (ncu <= 0) ncu = 256;
    if (occ <= 0) occ = 1;
    long cap = (long)occ * (long)ncu;
    int nblk = (int)(cap < 512 ? cap : 512);

    (void)hipMemsetAsync(bar, 0, sizeof(unsigned), stream);
    k_mega<<<dim3(nblk), dim3(256), 0, stream>>>(
        input_ids, enc, hidden, masks, slot, E, Wih, Whh, bih, bhh,
        Wgen, bgen, Wgate, bgate, out, gates_out, ml,
        E16, WH2, WL2, SH, SL, gigh, hbuf, ae, ctx, l16, ps, bar, nblk);
}

// Round 11
// 6427.642 us; speedup vs baseline: 2.0275x; 1.0658x over previous
//
#include <hip/hip_runtime.h>
#include <cstdint>
#include <cstddef>

// Problem constants (fixed by setup_inputs)
#define HDIM 768
#define VOCAB 32000
#define NGATES 5
#define NJ 30
#define NB 16
#define NS 512
#define NBJ (NB*NJ)      // 480
#define G3 2304          // 3*H
#define PR 608           // padded state rows
#define NBV 250          // vocab n-blocks

typedef _Float16 f16;
typedef _Float16 f16x4 __attribute__((ext_vector_type(4)));
typedef _Float16 f16x8 __attribute__((ext_vector_type(8)));
typedef float f32x4 __attribute__((ext_vector_type(4)));

#define GLOBAL_AS __attribute__((address_space(1)))
#define LDS_AS    __attribute__((address_space(3)))

// ---- system-scope relaxed accesses: compile to sc0 sc1 (bypass L1+L2 -> MALL),
//      with full compiler dependency tracking (no inline-asm hazards) ----
__device__ __forceinline__ float sysld_f32(const float* p) {
    return __hip_atomic_load(p, __ATOMIC_RELAXED, __HIP_MEMORY_SCOPE_SYSTEM);
}
__device__ __forceinline__ void syst_f32(float* p, float v) {
    __hip_atomic_store(p, v, __ATOMIC_RELAXED, __HIP_MEMORY_SCOPE_SYSTEM);
}
__device__ __forceinline__ unsigned long long sysld_u64(const void* p) {
    return __hip_atomic_load((const unsigned long long*)p, __ATOMIC_RELAXED, __HIP_MEMORY_SCOPE_SYSTEM);
}
__device__ __forceinline__ void syst_u64(void* p, unsigned long long v) {
    __hip_atomic_store((unsigned long long*)p, v, __ATOMIC_RELAXED, __HIP_MEMORY_SCOPE_SYSTEM);
}
__device__ __forceinline__ unsigned short sysld_u16(const void* p) {
    return __hip_atomic_load((const unsigned short*)p, __ATOMIC_RELAXED, __HIP_MEMORY_SCOPE_SYSTEM);
}
__device__ __forceinline__ void syst_u16(void* p, unsigned short v) {
    __hip_atomic_store((unsigned short*)p, v, __ATOMIC_RELAXED, __HIP_MEMORY_SCOPE_SYSTEM);
}
__device__ __forceinline__ float f16bits_to_f32(unsigned short u) {
    union { f16 h; unsigned short u; } c; c.u = u; return (float)c.h;
}
__device__ __forceinline__ unsigned short f32_to_f16bits(float v) {
    union { f16 h; unsigned short u; } c; c.h = (f16)v; return c.u;
}

// ---- lite grid barrier: relaxed counter only, NO fences (R9-proven to propagate) ----
__device__ __forceinline__ void gbar_lite(unsigned* bar, unsigned nblk, unsigned& ph) {
    __syncthreads();                 // drains vmcnt (incl. system-scope stores)
    ph += nblk;
    if (threadIdx.x == 0) {
        __hip_atomic_fetch_add(bar, 1u, __ATOMIC_RELAXED, __HIP_MEMORY_SCOPE_AGENT);
        while (__hip_atomic_load(bar, __ATOMIC_RELAXED, __HIP_MEMORY_SCOPE_AGENT) < ph)
            __builtin_amdgcn_s_sleep(16);
    }
    __syncthreads();
}

// ---- full barrier (R10-proven): once after phase 0, makes the cached constants
//      (E16/WH2/WL2) globally visible and purges stale/poison lines everywhere ----
__device__ __forceinline__ void gbar_full(unsigned* bar, unsigned nblk, unsigned& ph) {
    __syncthreads();
    ph += nblk;
    if (threadIdx.x == 0) {
        __threadfence();   // release: write back this XCD's L2
        __hip_atomic_fetch_add(bar, 1u, __ATOMIC_RELAXED, __HIP_MEMORY_SCOPE_AGENT);
        while (__hip_atomic_load(bar, __ATOMIC_RELAXED, __HIP_MEMORY_SCOPE_AGENT) < ph)
            __builtin_amdgcn_s_sleep(32);
        __threadfence();   // acquire: invalidate stale lines
    }
    __syncthreads();
}

// One LDS arena shared by all phases (block-local).
union SharedU {
    struct { f16 a[8][128][8]; f16 b[8][128][8]; float sbuf[2][128]; } g;  // 33.8 KB
    struct { float h[NJ][64]; float e[64][65]; } at;                       // 24.3 KB
    struct { float a[NJ][64]; } cx;                                        // 7.5 KB
    struct { float red[256]; float rv[256]; int ri[256]; } rd;             // 3 KB
};

// ---- split-f16 MFMA GEMM tile: C = A * B^T ----
// A (mutable state): reg-staged via system-scope loads (always fresh from MALL).
// B (constants, post-phase-0): global_load_lds fast path.
// C: system-scope stores (fp32 or f16+psum).
__device__ __forceinline__ void gemm_tile(
        const f16* __restrict__ Ah, const f16* __restrict__ Al,
        const f16* __restrict__ Bh, const f16* __restrict__ Bl,
        float* __restrict__ Cf, f16* __restrict__ Ch, float* __restrict__ psum,
        int M, long ldc, int kdim, int nspan, int bx, int by, SharedU* sh) {
    const int tid = threadIdx.x;
    const int m0 = bx*128, n0 = by*128;
    const int w = tid >> 6, lane = tid & 63;
    const int wm = (w >> 1)*64, wn = (w & 1)*64;
    const int lr = lane & 15, lg = lane >> 4;

    f32x4 acc[4][4] = {};

    for (int sp = 0; sp < nspan; ++sp) {
        const f16* Ap = (sp < 2) ? Ah : Al;
        const f16* Bp = (sp == 1) ? Bl : Bh;
        for (int kc = 0; kc < kdim; kc += 64) {
            #pragma unroll
            for (int i = 0; i < 4; ++i) {
                const int idx = w*4 + i;                  // 0..15
                const int c = idx >> 1;                    // k-octet
                const int rl = (idx & 1)*64 + lane;        // row 0..127
                // A: system-scope loads -> LDS (16 B/lane)
                const f16* ga = Ap + (long)(m0 + rl)*kdim + kc + c*8;
                unsigned long long lo = sysld_u64(ga);
                unsigned long long hi = sysld_u64(ga + 4);
                char* d = (char*)&sh->g.a[0][0][0] + idx*1024 + lane*16;
                *(unsigned long long*)d = lo;
                *((unsigned long long*)d + 1) = hi;
                // B: async global->LDS (cached path, constants)
                const f16* gb = Bp + (long)(n0 + rl)*kdim + kc + c*8;
                __builtin_amdgcn_global_load_lds(
                    (const GLOBAL_AS unsigned int*)gb,
                    (LDS_AS unsigned int*)((char*)&sh->g.b[0][0][0] + idx*1024), 16, 0, 0);
            }
            __syncthreads();
            #pragma unroll
            for (int kk = 0; kk < 2; ++kk) {
                const int c = kk*4 + lg;
                f16x8 af[4], bf[4];
                #pragma unroll
                for (int mi = 0; mi < 4; ++mi) af[mi] = *(const f16x8*)&sh->g.a[c][wm + mi*16 + lr][0];
                #pragma unroll
                for (int nf = 0; nf < 4; ++nf) bf[nf] = *(const f16x8*)&sh->g.b[c][wn + nf*16 + lr][0];
                #pragma unroll
                for (int mi = 0; mi < 4; ++mi)
                    #pragma unroll
                    for (int nf = 0; nf < 4; ++nf)
                        acc[mi][nf] = __builtin_amdgcn_mfma_f32_16x16x32_f16(af[mi], bf[nf], acc[mi][nf], 0, 0, 0);
            }
            __syncthreads();
        }
    }

    if (Ch != nullptr) {
        #pragma unroll
        for (int mi = 0; mi < 4; ++mi)
            #pragma unroll
            for (int nf = 0; nf < 4; ++nf) {
                int col = n0 + wn + nf*16 + lr;
                int rowb = m0 + wm + mi*16 + lg*4;
                #pragma unroll
                for (int r = 0; r < 4; ++r) {
                    int row = rowb + r;
                    if (row < M) syst_u16(&Ch[(long)row*ldc + col], f32_to_f16bits(acc[mi][nf][r]));
                }
            }
    } else {
        #pragma unroll
        for (int mi = 0; mi < 4; ++mi)
            #pragma unroll
            for (int nf = 0; nf < 4; ++nf) {
                int col = n0 + wn + nf*16 + lr;
                int rowb = m0 + wm + mi*16 + lg*4;
                #pragma unroll
                for (int r = 0; r < 4; ++r) {
                    int row = rowb + r;
                    if (row < M) syst_f32(&Cf[(long)row*ldc + col], acc[mi][nf][r]);
                }
            }
    }

    // fused row-sumexp partials over f16-rounded logits (no-max vocab softmax)
    if (psum != nullptr) {
        #pragma unroll
        for (int mi = 0; mi < 4; ++mi) {
            #pragma unroll
            for (int r = 0; r < 4; ++r) {
                float s = 0.f;
                #pragma unroll
                for (int nf = 0; nf < 4; ++nf) s += expf((float)(f16)acc[mi][nf][r]);
                s += __shfl_xor(s, 1); s += __shfl_xor(s, 2);
                s += __shfl_xor(s, 4); s += __shfl_xor(s, 8);
                if (lr == 0) sh->g.sbuf[w & 1][wm + mi*16 + lg*4 + r] = s;
            }
        }
        __syncthreads();
        if (tid < 128) syst_f32(&psum[(long)by*512 + m0 + tid],
                                sh->g.sbuf[0][tid] + sh->g.sbuf[1][tid]);
        __syncthreads();
    }
}

// ---- the whole decode in one kernel; fence-free barriers in steady state ----
__launch_bounds__(256, 2)
__global__ void k_mega(const int* __restrict__ ids, const float* __restrict__ enc,
                       const float* __restrict__ hidden, const int* __restrict__ masks,
                       const int* __restrict__ slot, const float* __restrict__ E,
                       const float* __restrict__ Wih, const float* __restrict__ Whh,
                       const float* __restrict__ bih, const float* __restrict__ bhh,
                       const float* __restrict__ Wgen, const float* __restrict__ bgen,
                       const float* __restrict__ Wgate, const float* __restrict__ bgate,
                       float* __restrict__ out, float* __restrict__ gates_out, int ml,
                       f16* __restrict__ E16, f16* __restrict__ WH2, f16* __restrict__ WL2,
                       f16* __restrict__ SH, f16* __restrict__ SL,
                       float* __restrict__ gigh, float* __restrict__ hbuf,
                       float* __restrict__ ae, float* __restrict__ ctx,
                       f16* __restrict__ l16, float* __restrict__ ps,
                       unsigned* __restrict__ bar, int nblk) {
    __shared__ SharedU sh;
    __shared__ int s_bidx;
    unsigned ph = 0;

    const int blk = blockIdx.x, tid = threadIdx.x;
    f16* wH = SH;                       f16* wL = SL;
    f16* hH = SH + (size_t)PR*HDIM;     f16* hL = SL + (size_t)PR*HDIM;
    float* gi = gigh;                   float* gh = gigh + (size_t)NBJ*G3;
    const long ldrow = (long)ml*VOCAB;

    // ---------- phase 0: casts + init (normal stores; gbar_full flushes) ----------
    {
        const long nE = (long)VOCAB*HDIM;
        for (long i = (long)(blk*256 + tid)*4; i < nE; i += (long)nblk*256*4) {
            float4 v = *(const float4*)&E[i];
            f16x4 o = { (f16)v.x, (f16)v.y, (f16)v.z, (f16)v.w };
            *(f16x4*)&E16[i] = o;
        }
        const long nW = (long)G3*HDIM;
        for (long i = (long)(blk*256 + tid)*4; i < nW; i += (long)nblk*256*4) {
            float4 a = *(const float4*)&Wih[i];
            f16x4 h = { (f16)a.x, (f16)a.y, (f16)a.z, (f16)a.w };
            f16x4 l = { (f16)(a.x-(float)h[0]), (f16)(a.y-(float)h[1]),
                        (f16)(a.z-(float)h[2]), (f16)(a.w-(float)h[3]) };
            *(f16x4*)&WH2[i] = h; *(f16x4*)&WL2[i] = l;
            float4 b = *(const float4*)&Whh[i];
            f16x4 h2 = { (f16)b.x, (f16)b.y, (f16)b.z, (f16)b.w };
            f16x4 l2 = { (f16)(b.x-(float)h2[0]), (f16)(b.y-(float)h2[1]),
                         (f16)(b.z-(float)h2[2]), (f16)(b.w-(float)h2[3]) };
            *(f16x4*)&WH2[nW + i] = h2; *(f16x4*)&WL2[nW + i] = l2;
        }
        for (int i = blk*256 + tid; i < NBJ*HDIM; i += nblk*256) {
            int hh = i % HDIM, row = i / HDIM;
            int b = row / NJ, j = row % NJ;
            float s = 0.f;
            #pragma unroll
            for (int l = 0; l < 4; ++l) s += E[(long)slot[j*4+l]*HDIM + hh];
            f16 sh16 = (f16)s;
            wH[i] = sh16; wL[i] = (f16)(s - (float)sh16);
            float hv = hidden[b*HDIM + hh];
            hbuf[i] = hv;
            f16 hh16 = (f16)hv;
            hH[i] = hh16; hL[i] = (f16)(hv - (float)hh16);
        }
    }
    gbar_full(bar, nblk, ph);   // ONE heavy barrier: constants visible + stale lines purged

    for (int t = 0; t < ml; ++t) {
        // ---------- P1: GRU gemms (144 tiles): gi = w@Wih^T, gh = h@Whh^T ----------
        for (int bi = blk; bi < 144; bi += nblk) {
            int z = bi / 72, r = bi % 72, bx = r & 3, by = r >> 2;
            gemm_tile(z ? hH : wH, z ? hL : wL,
                      WH2 + (size_t)z*G3*HDIM, WL2 + (size_t)z*G3*HDIM,
                      z ? gh : gi, nullptr, nullptr,
                      NBJ, (long)G3, HDIM, 3, bx, by, &sh);
        }
        gbar_lite(bar, nblk, ph);

        // ---------- P2: GRU elementwise ----------
        for (int i = blk*256 + tid; i < NBJ*HDIM; i += nblk*256) {
            int c = i % HDIM; long row = i / HDIM;
            long base = row*G3;
            float r = sysld_f32(&gi[base + c])        + bih[c]        + sysld_f32(&gh[base + c])        + bhh[c];
            float z = sysld_f32(&gi[base + 768 + c])  + bih[768 + c]  + sysld_f32(&gh[base + 768 + c])  + bhh[768 + c];
            float hn  = sysld_f32(&gh[base + 1536 + c]) + bhh[1536 + c];
            float in_ = sysld_f32(&gi[base + 1536 + c]) + bih[1536 + c];
            r = 1.f/(1.f + expf(-r));
            z = 1.f/(1.f + expf(-z));
            float n = tanhf(in_ + r*hn);
            float hv = (1.f - z)*n + z*sysld_f32(&hbuf[i]);
            syst_f32(&hbuf[i], hv);
            f16 h16 = (f16)hv;
            syst_u16(&hH[i], f32_to_f16bits(hv));
            syst_u16(&hL[i], f32_to_f16bits(hv - (float)h16));
        }
        gbar_lite(bar, nblk, ph);

        // ---------- PA: attn scores (128 units) + vocab logits (1000 units) ----------
        for (int u = blk; u < 128 + 4*NBV; u += nblk) {
            __syncthreads();   // guard LDS arena reuse between loop iterations
            if (u < 128) {
                const int b = u >> 3, s0 = (u & 7)*64;
                const int s = tid & 63, jg = tid >> 6;
                float acc[8] = {};
                for (int kc = 0; kc < HDIM; kc += 64) {
                    for (int idx = tid; idx < NJ*64; idx += 256) {
                        int j = idx >> 6, k = idx & 63;
                        sh.at.h[j][k] = sysld_f32(&hbuf[((long)(b*NJ + j))*HDIM + kc + k]);
                    }
                    #pragma unroll
                    for (int i = 0; i < 4; ++i) {
                        int id = tid + i*256;
                        int ss = id >> 4, kq = (id & 15)*4;
                        float4 v = *(const float4*)&enc[((long)b*NS + s0 + ss)*HDIM + kc + kq];
                        sh.at.e[ss][kq+0] = v.x; sh.at.e[ss][kq+1] = v.y;
                        sh.at.e[ss][kq+2] = v.z; sh.at.e[ss][kq+3] = v.w;
                    }
                    __syncthreads();
                    for (int k = 0; k < 64; ++k) {
                        float e = sh.at.e[s][k];
                        #pragma unroll
                        for (int i = 0; i < 8; ++i) {
                            int j = jg + i*4;
                            if (j < NJ) acc[i] += sh.at.h[j][k]*e;
                        }
                    }
                    __syncthreads();
                }
                #pragma unroll
                for (int i = 0; i < 8; ++i) {
                    int j = jg + i*4;
                    if (j < NJ) syst_f32(&ae[((long)(b*NJ + j))*NS + s0 + s], acc[i]);
                }
            } else {
                const int vt = u - 128;
                gemm_tile(hH, nullptr, E16, nullptr, nullptr, l16, ps,
                          NBJ, (long)VOCAB, HDIM, 1, vt & 3, vt >> 2, &sh);
            }
        }
        gbar_lite(bar, nblk, ph);

        // ---------- P4: masked softmax over S (in place) ----------
        for (int row = blk; row < NBJ; row += nblk) {
            __syncthreads();
            const int b = row / NJ;
            float x0 = sysld_f32(&ae[(long)row*NS + tid]);
            float x1 = sysld_f32(&ae[(long)row*NS + tid + 256]);
            if (masks[b*NS + tid]       != 1) x0 = -1e9f;
            if (masks[b*NS + tid + 256] != 1) x1 = -1e9f;
            sh.rd.red[tid] = fmaxf(x0, x1); __syncthreads();
            for (int o = 128; o > 0; o >>= 1) { if (tid < o) sh.rd.red[tid] = fmaxf(sh.rd.red[tid], sh.rd.red[tid+o]); __syncthreads(); }
            float m = sh.rd.red[0]; __syncthreads();
            float e0 = expf(x0 - m), e1 = expf(x1 - m);
            sh.rd.red[tid] = e0 + e1; __syncthreads();
            for (int o = 128; o > 0; o >>= 1) { if (tid < o) sh.rd.red[tid] += sh.rd.red[tid+o]; __syncthreads(); }
            float inv = 1.f/sh.rd.red[0];
            syst_f32(&ae[(long)row*NS + tid],       e0*inv);
            syst_f32(&ae[(long)row*NS + tid + 256], e1*inv);
        }
        gbar_lite(bar, nblk, ph);

        // ---------- P5: context (96 tiles; enc read exactly once) ----------
        for (int bi = blk; bi < 96; bi += nblk) {
            __syncthreads();
            const int b = bi / 6, ht = bi % 6;
            const int hh = ht*128 + (tid & 127);
            const int jg = tid >> 7;
            float acc[15] = {};
            for (int sc = 0; sc < NS; sc += 64) {
                for (int idx = tid; idx < NJ*64; idx += 256) {
                    int j = idx >> 6, s = idx & 63;
                    sh.cx.a[j][s] = sysld_f32(&ae[((long)(b*NJ + j))*NS + sc + s]);
                }
                __syncthreads();
                for (int s = 0; s < 64; ++s) {
                    float e = enc[((long)b*NS + sc + s)*HDIM + hh];
                    #pragma unroll
                    for (int i = 0; i < 15; ++i) acc[i] += sh.cx.a[jg + i*2][s]*e;
                }
                __syncthreads();
            }
            #pragma unroll
            for (int i = 0; i < 15; ++i)
                syst_f32(&ctx[((long)(b*NJ + jg + i*2))*HDIM + hh], acc[i]);
        }
        gbar_lite(bar, nblk, ph);

        // ---------- P8: finalize — pgen(+gates) + scale + argmax + scatter + next-w ----------
        for (int row = blk; row < NBJ; row += nblk) {
            __syncthreads();
            const int b = row / NJ;
            float* base = out + (long)row*ldrow + (long)t*VOCAB;
            const f16* lb = l16 + (long)row*VOCAB;

            // p_gen = sigmoid([w,h,ctx] . Wgen + b)
            float acc = 0.f;
            for (int x = tid; x < HDIM; x += 256) {
                float wv = f16bits_to_f32(sysld_u16(&wH[(long)row*HDIM + x]))
                         + f16bits_to_f32(sysld_u16(&wL[(long)row*HDIM + x]));
                acc += wv*Wgen[x] + sysld_f32(&hbuf[(long)row*HDIM + x])*Wgen[768 + x]
                     + sysld_f32(&ctx[(long)row*HDIM + x])*Wgen[1536 + x];
            }
            sh.rd.red[tid] = acc; __syncthreads();
            for (int o = 128; o > 0; o >>= 1) { if (tid < o) sh.rd.red[tid] += sh.rd.red[tid+o]; __syncthreads(); }
            const float pg = 1.f/(1.f + expf(-(sh.rd.red[0] + bgen[0])));
            __syncthreads();

            if (t == 0) {
                for (int g = 0; g < NGATES; ++g) {
                    float a = 0.f;
                    for (int x = tid; x < HDIM; x += 256)
                        a += sysld_f32(&ctx[(long)row*HDIM + x])*Wgate[x*NGATES + g];
                    sh.rd.red[tid] = a; __syncthreads();
                    for (int o = 128; o > 0; o >>= 1) { if (tid < o) sh.rd.red[tid] += sh.rd.red[tid+o]; __syncthreads(); }
                    if (tid == 0) gates_out[row*NGATES + g] = sh.rd.red[0] + bgate[g];
                    __syncthreads();
                }
            }

            // denominator from psum partials
            float s = 0.f;
            for (int nb = tid; nb < NBV; nb += 256) s += sysld_f32(&ps[(long)nb*512 + row]);
            sh.rd.red[tid] = s; __syncthreads();
            for (int o = 128; o > 0; o >>= 1) { if (tid < o) sh.rd.red[tid] += sh.rd.red[tid+o]; __syncthreads(); }
            const float scale = pg / sh.rd.red[0];

            // p = pgen*exp(l)/sum (u64 loads: 4 f16/iter), track argmax (first-index ties)
            float bv = -1.f; int bi2 = 0;
            for (int v4 = tid*4; v4 < VOCAB; v4 += 1024) {
                unsigned long long q = sysld_u64(&lb[v4]);
                float4 o4;
                float* ov = (float*)&o4;
                #pragma unroll
                for (int k = 0; k < 4; ++k) {
                    float val = scale*expf(f16bits_to_f32((unsigned short)(q >> (16*k))));
                    ov[k] = val;
                    if (val > bv) { bv = val; bi2 = v4 + k; }
                }
                *(float4*)&base[v4] = o4;
            }
            sh.rd.rv[tid] = bv; sh.rd.ri[tid] = bi2; __syncthreads();
            for (int o = 128; o > 0; o >>= 1) {
                if (tid < o) {
                    float v2 = sh.rd.rv[tid+o]; int i2 = sh.rd.ri[tid+o];
                    if (v2 > sh.rd.rv[tid] || (v2 == sh.rd.rv[tid] && i2 < sh.rd.ri[tid])) { sh.rd.rv[tid] = v2; sh.rd.ri[tid] = i2; }
                }
                __syncthreads();
            }
            float v0 = sh.rd.rv[0]; int i0 = sh.rd.ri[0];
            __syncthreads();   // base[] stores drained before atomics

            // pointer scatter; temporally-last add on an address = true final value
            const float cp = 1.f - pg;
            float sv = -1.f; int si = 0x7FFFFFFF;
            for (int ss = tid; ss < NS; ss += 256) {
                int id = ids[(long)b*NS + ss];
                float add = cp * sysld_f32(&ae[(long)row*NS + ss]);
                float old = atomicAdd(base + id, add);
                float cand = old + add;
                if (cand > sv || (cand == sv && id < si)) { sv = cand; si = id; }
            }
            sh.rd.rv[tid] = sv; sh.rd.ri[tid] = si; __syncthreads();
            for (int o = 128; o > 0; o >>= 1) {
                if (tid < o) {
                    float v2 = sh.rd.rv[tid+o]; int i2 = sh.rd.ri[tid+o];
                    if (v2 > sh.rd.rv[tid] || (v2 == sh.rd.rv[tid] && i2 < sh.rd.ri[tid])) { sh.rd.rv[tid] = v2; sh.rd.ri[tid] = i2; }
                }
                __syncthreads();
            }
            if (tid == 0) {
                float vv = v0; int ii = i0;
                if (sh.rd.rv[0] > vv || (sh.rd.rv[0] == vv && sh.rd.ri[0] < ii)) { vv = sh.rd.rv[0]; ii = sh.rd.ri[0]; }
                s_bidx = ii;
            }
            __syncthreads();
            const int idx = s_bidx;
            for (int x = tid; x < HDIM; x += 256) {
                float ev = E[(long)idx*HDIM + x];
                f16 eh = (f16)ev;
                syst_u16(&wH[(long)row*HDIM + x], f32_to_f16bits(ev));
                syst_u16(&wL[(long)row*HDIM + x], f32_to_f16bits(ev - (float)eh));
            }
        }
        gbar_lite(bar, nblk, ph);
    }
}

// ---------------- host ----------------
extern "C" void kernel_launch(void* const* d_in, const int* in_sizes, int n_in,
                              void* d_out, int out_size, void* d_ws, size_t ws_size,
                              hipStream_t stream) {
    const int*   input_ids = (const int*)  d_in[0];
    const float* enc       = (const float*)d_in[1];
    const float* hidden    = (const float*)d_in[2];
    const int*   masks     = (const int*)  d_in[3];
    const int*   slot      = (const int*)  d_in[4];
    const float* E     = (const float*)d_in[6];
    const float* Wih   = (const float*)d_in[7];
    const float* Whh   = (const float*)d_in[8];
    const float* bih   = (const float*)d_in[9];
    const float* bhh   = (const float*)d_in[10];
    const float* Wgen  = (const float*)d_in[11];
    const float* bgen  = (const float*)d_in[12];
    const float* Wgate = (const float*)d_in[13];
    const float* bgate = (const float*)d_in[14];

    int ml = (out_size / NBJ - NGATES) / VOCAB;   // = 8
    float* out = (float*)d_out;
    float* gates_out = out + (long)NBJ*ml*VOCAB;

    // workspace carve (256B aligned)
    char* ws = (char*)d_ws;
    auto carve = [&](size_t bytes) { char* p = ws; ws += (bytes + 255) & ~(size_t)255; return p; };
    unsigned* bar = (unsigned*)carve(256);
    f16*   E16   = (f16*)carve((size_t)VOCAB*HDIM*2);
    f16*   WH2   = (f16*)carve((size_t)2*G3*HDIM*2);   // WihH | WhhH
    f16*   WL2   = (f16*)carve((size_t)2*G3*HDIM*2);
    f16*   SH    = (f16*)carve((size_t)2*PR*HDIM*2);   // wH | hH (padded rows)
    f16*   SL    = (f16*)carve((size_t)2*PR*HDIM*2);
    float* gigh  = (float*)carve((size_t)2*NBJ*G3*4);  // gi | gh
    float* hbuf  = (float*)carve((size_t)NBJ*HDIM*4);
    float* ae    = (float*)carve((size_t)NBJ*NS*4);
    float* ctx   = (float*)carve((size_t)NBJ*HDIM*4);
    f16*   l16   = (f16*)carve((size_t)NBJ*VOCAB*2);
    float* ps    = (float*)carve((size_t)NBV*512*4);

    // co-residency-safe grid size
    int dev = 0; (void)hipGetDevice(&dev);
    int ncu = 0; (void)hipDeviceGetAttribute(&ncu, hipDeviceAttributeMultiprocessorCount, dev);
    int occ = 0; (void)hipOccupancyMaxActiveBlocksPerMultiprocessor(&occ, (const void*)k_mega, 256, 0);
    if (ncu <= 0) ncu = 256;
    if (occ <= 0) occ = 1;
    long cap = (long)occ * (long)ncu;
    int nblk = (int)(cap < 512 ? cap : 512);

    (void)hipMemsetAsync(bar, 0, sizeof(unsigned), stream);
    k_mega<<<dim3(nblk), dim3(256), 0, stream>>>(
        input_ids, enc, hidden, masks, slot, E, Wih, Whh, bih, bhh,
        Wgen, bgen, Wgate, bgate, out, gates_out, ml,
        E16, WH2, WL2, SH, SL, gigh, hbuf, ae, ctx, l16, ps, bar, nblk);
}